// Round 4
// baseline (884.149 us; speedup 1.0000x reference)
//
#include <hip/hip_runtime.h>
#include <stdint.h>

// Autoregressive LSTM, B=256, H=1024, T=128.
//  - x==h for steps >=2  => combined weights W = Wi+Wh (4 GEMMs/step)
//  - weights persistent in REGISTERS (B-frags, 128 VGPR/wave); no weight LDS
//  - A (=h[s-1]) staged into LDS per step via global_load_lds (16-deep swizzle)
//  - WG = 32 batch rows x 128 gate cols; mt=bid&7 => recurrence is XCD-local
//  - 8 waves: 2 col-halves x 4-way K-split; partials in DEDICATED LDS region
//  - sync: per-wave flag atomicAdd (consumer polls ==8); out-store after flag;
//    3 barriers/step (was 5)

#define BATCH 256
#define HID   1024

typedef __bf16 bf16_t;
typedef bf16_t bf16x8 __attribute__((ext_vector_type(8)));
typedef float  f32x16 __attribute__((ext_vector_type(16)));
typedef float  f32x4  __attribute__((ext_vector_type(4)));
typedef float  f32x2  __attribute__((ext_vector_type(2)));
typedef unsigned int u32;
typedef unsigned long long u64;

// ---- workspace layout (bytes) ----
// [0, 64MB)   : h shadow bf16 [T][256][1024]  (Wi overlaid on tail)
// [64MB,72MB) : combined weights Wc bf16 [4096][1024], row = j*4 + gate
// [72MB,+16K) : combined bias f32 [4096]
// [72MB+64K)  : flags u32 [T][8][32]  (counter, producers add 1 per wave, full=8)
#define WC_OFF    (64ull << 20)
#define BIAS_OFF  (72ull << 20)
#define FLAG_OFF  ((72ull << 20) + (1ull << 16))

// LDS: [0,65536) A region (32 rows x 2048B, 16-deep XOR swizzle)
//      [65536,131072) K-split partials [4][32][128] f32 (disjoint from A!)
//      [131072,+512) bias slice
#define LDS_BYTES 131584   // forces 1 WG/CU

__device__ __forceinline__ void gload_lds16(const void* g, void* l) {
  auto gp = reinterpret_cast<const __attribute__((address_space(1))) unsigned int*>(
      reinterpret_cast<uintptr_t>(g));
  auto lp = reinterpret_cast<__attribute__((address_space(3))) unsigned int*>(
      reinterpret_cast<uintptr_t>(l));
  __builtin_amdgcn_global_load_lds(gp, lp, 16, 0, 0);
}

// merged prep (blocks 0..4095: combine weights) + init (blocks 4096..4351)
__global__ __launch_bounds__(256) void k_setup(
    const float* __restrict__ wf, const float* __restrict__ wi_,
    const float* __restrict__ wo, const float* __restrict__ wc,
    const float* __restrict__ hf, const float* __restrict__ hi,
    const float* __restrict__ ho, const float* __restrict__ hc,
    const float* __restrict__ bf_, const float* __restrict__ bi_,
    const float* __restrict__ bo_, const float* __restrict__ bc_,
    const float* __restrict__ hbf, const float* __restrict__ hbi,
    const float* __restrict__ hbo, const float* __restrict__ hbc,
    const float* __restrict__ x0, float* __restrict__ out,
    bf16_t* __restrict__ Wc, bf16_t* __restrict__ Wi, float* __restrict__ bias,
    bf16_t* __restrict__ hsh, u32* __restrict__ flags, int nflags)
{
  int bid = blockIdx.x;
  if (bid < 4096) {                // ---- weight prep: row = j*4 + g ----
    int r = bid, j = r >> 2, g = r & 3;
    const float *wip, *whp, *bip, *bhp;
    switch (g) {
      case 0:  wip = wf;  whp = hf; bip = bf_; bhp = hbf; break;
      case 1:  wip = wi_; whp = hi; bip = bi_; bhp = hbi; break;
      case 2:  wip = wo;  whp = ho; bip = bo_; bhp = hbo; break;
      default: wip = wc;  whp = hc; bip = bc_; bhp = hbc; break;
    }
    int k = threadIdx.x * 4;
    f32x4 a = *(const f32x4*)(wip + (size_t)j * HID + k);
    f32x4 b = *(const f32x4*)(whp + (size_t)j * HID + k);
    union { bf16_t h[4]; u64 v; } pc, pi;
#pragma unroll
    for (int t = 0; t < 4; ++t) { pc.h[t] = (bf16_t)(a[t] + b[t]); pi.h[t] = (bf16_t)a[t]; }
    *(u64*)(Wc + (size_t)r * HID + k) = pc.v;
    *(u64*)(Wi + (size_t)r * HID + k) = pi.v;
    if (threadIdx.x == 0) bias[r] = bip[j] + bhp[j];
  } else {                         // ---- init: x0 -> out[0], hsh[0]; zero flags ----
    int gid = (bid - 4096) * 256 + threadIdx.x;   // 65536 threads x 4 elems
    int i = gid * 4;
    f32x4 v = *(const f32x4*)(x0 + i);
    __builtin_nontemporal_store(v, (f32x4*)(out + i));
    union { bf16_t h[4]; u64 u; } p;
#pragma unroll
    for (int t = 0; t < 4; ++t) p.h[t] = (bf16_t)v[t];
    *(u64*)(hsh + i) = p.u;
    if (gid < nflags) flags[gid] = 0;
  }
}

__global__ __launch_bounds__(512, 2) void k_lstm(
    const bf16_t* __restrict__ Wc, const bf16_t* __restrict__ Wi,
    const float* __restrict__ bias, bf16_t* __restrict__ hsh,
    u32* __restrict__ flags, float* __restrict__ out, int T)
{
  extern __shared__ char lds[];
  char*  plds = lds + 65536;           // partials [4][32][128] f32
  float* blds = (float*)(lds + 131072);

  const int tid  = threadIdx.x;
  const int bid  = blockIdx.x;
  const int mt   = bid & 7;          // XCD id == batch group (32 rows): local L2
  const int jt   = bid >> 3;         // 0..31: 32 hidden cols / 128 gate rows
  const int lane = tid & 63;
  const int wv   = tid >> 6;         // 0..7
  const int wn   = wv & 1;           // col half (2 tiles of 32 gate cols each)
  const int ks   = wv >> 1;          // k quarter (256 of 1024)
  const int al   = lane & 31, kh = lane >> 5;
  const int row0 = jt << 7;          // first gate row of this WG

  if (tid < 128) blds[tid] = bias[row0 + tid];

  // epilogue mapping: thread -> (batch row eb, hidden col pair jp)
  const int eb   = tid >> 4;         // 0..31
  const int jp   = (tid & 15) << 1;  // 0,2,..,30
  const int bswz = (eb & 7) << 4;
  const size_t eoff_base = ((size_t)((mt << 5) + eb) << 10) + (jt << 5) + jp;
  float cst0 = 0.f, cst1 = 0.f;      // c-state (2 cells/thread), in VGPRs

  const int aswz = (al & 15) << 4;   // 16-deep: 2-way LDS access = free
  const int kb0  = (ks << 9) + (kh << 4);
  bf16x8 breg0[16], breg1[16];       // persistent B fragments (128 VGPRs)

  for (int s = 1; s < T; ++s) {
    // ---- B: poll (wave0 only; overlaps other waves' epilogue tails) ----
    if (s >= 2 && wv == 0) {
      const u32* f = flags + ((size_t)(s - 1) << 8) + (mt << 5);
      u32 v = (lane < 32)
          ? __hip_atomic_load(f + lane, __ATOMIC_RELAXED, __HIP_MEMORY_SCOPE_AGENT)
          : 8u;
      int guard = 0;
      while (__any(v != 8u) && guard < (1 << 20)) {
        __builtin_amdgcn_s_sleep(1);
        if (lane < 32 && v != 8u)
          v = __hip_atomic_load(f + lane, __ATOMIC_RELAXED, __HIP_MEMORY_SCOPE_AGENT);
        ++guard;
      }
    }
    __syncthreads();                                    // C (also loop barrier)

    // ---- D: stage h[s-1] slice (32 rows x 2KB = 64KB) into LDS ----
    // linear LDS dest (gload_lds requirement), 16-deep pre-swizzled global src
    {
      const char* hp = (const char*)hsh + ((size_t)(s - 1) << 19) + ((size_t)mt << 16);
#pragma unroll
      for (int c = 0; c < 8; ++c) {
        int d = (c << 13) + (tid << 4);
        int row = d >> 11, off = d & 2047;
        gload_lds16(hp + row * 2048 + (off ^ ((row & 15) << 4)), lds + d);
      }
    }
    if (s <= 2) {  // B-frags: step 1 = Wi (h==0), step 2 = combined Wc
      const bf16_t* WB  = (s == 1) ? Wi : Wc;
      const bf16_t* wb0 = WB + ((size_t)(row0 + (wn << 6) + al) << 10) + (ks << 8) + (kh << 3);
      const bf16_t* wb1 = wb0 + (32 << 10);
#pragma unroll
      for (int kk = 0; kk < 16; ++kk) {
        breg0[kk] = *(const bf16x8*)(wb0 + (kk << 4));
        breg1[kk] = *(const bf16x8*)(wb1 + (kk << 4));
      }
    }
    asm volatile("s_waitcnt vmcnt(0)" ::: "memory");    // E: stages (+old out) done
    __syncthreads();                                    // F

    // ---- G: MFMA, 2 col-tiles per A read, K-range 256 per wave ----
    f32x16 acc0 = {}, acc1 = {};
    {
      const char* abase = lds + al * 2048;
#pragma unroll
      for (int kk = 0; kk < 16; ++kk) {
        bf16x8 a = *(const bf16x8*)(abase + ((kb0 + (kk << 5)) ^ aswz));
        acc0 = __builtin_amdgcn_mfma_f32_32x32x16_bf16(a, breg0[kk], acc0, 0, 0, 0);
        acc1 = __builtin_amdgcn_mfma_f32_32x32x16_bf16(a, breg1[kk], acc1, 0, 0, 0);
      }
    }

    // ---- H: write K-split partials (dedicated region; no barrier needed) ----
#pragma unroll
    for (int r = 0; r < 16; ++r) {
      int prow = (r & 3) + ((r >> 2) << 3) + (kh << 2);
      char* pb = plds + (ks << 14) + prow * 512;
      int sw = (prow & 7) << 4;
      *(float*)(pb + ((((wn << 6) + al) << 2) ^ sw))      = acc0[r];
      *(float*)(pb + ((((wn << 6) + 32 + al) << 2) ^ sw)) = acc1[r];
    }
    __syncthreads();                                    // I

    // ---- J: epilogue — reduce 4 partials, gate math ----
    float hv[2];
#pragma unroll
    for (int e = 0; e < 2; ++e) {
      int cb = (jp + e) << 4;        // gate-quad byte offset
      int co = cb ^ bswz;
      const char* pb = plds + eb * 512;
      f32x4 p = *(const f32x4*)(pb + co);
      p += *(const f32x4*)(pb + 16384 + co);
      p += *(const f32x4*)(pb + 32768 + co);
      p += *(const f32x4*)(pb + 49152 + co);
      f32x4 bb = *(const f32x4*)((const char*)blds + cb);
      float xf = p[0] + bb[0], xi = p[1] + bb[1], xo = p[2] + bb[2], xc = p[3] + bb[3];
      float gf = 1.f / (1.f + __expf(-xf));
      float gi = 1.f / (1.f + __expf(-xi));
      float go = 1.f / (1.f + __expf(-xo));
      float cp = tanhf(xc);
      float &cs = e ? cst1 : cst0;
      cs = gf * cs + gi * cp;
      hv[e] = go * tanhf(cs);
    }

    // ---- K: h-shadow store (fresh address + agent scope => never stale) ----
    union { bf16_t h2[2]; u32 u; } pk;
    pk.h2[0] = (bf16_t)hv[0]; pk.h2[1] = (bf16_t)hv[1];
    __hip_atomic_store((u32*)(hsh + ((size_t)s << 18) + eoff_base), pk.u,
                       __ATOMIC_RELAXED, __HIP_MEMORY_SCOPE_AGENT);
    // ---- L: per-wave drain of OWN h-stores only ----
    asm volatile("s_waitcnt vmcnt(0)" ::: "memory");
    // ---- M: per-wave flag (consumers poll for ==8) ----
    if (lane == 0)
      __hip_atomic_fetch_add(flags + ((size_t)s << 8) + (mt << 5) + jt, 1u,
                             __ATOMIC_RELAXED, __HIP_MEMORY_SCOPE_AGENT);
    asm volatile("" ::: "memory");
    // ---- N: out store AFTER flag — its HBM ack no longer gates consumers ----
    f32x2 ov; ov[0] = hv[0]; ov[1] = hv[1];
    __builtin_nontemporal_store(ov, (f32x2*)(out + ((size_t)s << 18) + eoff_base));
  }
}

extern "C" void kernel_launch(void* const* d_in, const int* in_sizes, int n_in,
                              void* d_out, int out_size, void* d_ws, size_t ws_size,
                              hipStream_t stream) {
  const float* Wif = (const float*)d_in[0];
  const float* bif = (const float*)d_in[1];
  const float* Wii = (const float*)d_in[2];
  const float* bii = (const float*)d_in[3];
  const float* Wio = (const float*)d_in[4];
  const float* bio = (const float*)d_in[5];
  const float* Wic = (const float*)d_in[6];
  const float* bic = (const float*)d_in[7];
  const float* Whf = (const float*)d_in[8];
  const float* bhf = (const float*)d_in[9];
  const float* Whi = (const float*)d_in[10];
  const float* bhi = (const float*)d_in[11];
  const float* Who = (const float*)d_in[12];
  const float* bho = (const float*)d_in[13];
  const float* Whc = (const float*)d_in[14];
  const float* bhc = (const float*)d_in[15];
  const float* x0  = (const float*)d_in[16];
  const int T = out_size / (BATCH * HID);          // 128

  char* ws = (char*)d_ws;
  bf16_t* hsh  = (bf16_t*)ws;
  bf16_t* WcP  = (bf16_t*)(ws + WC_OFF);
  // Wi (step-1 weights) overlaid on h-shadow tail (steps T-16..T-1): only read
  // during step 1's B-load, overwritten ~100 steps later.
  bf16_t* WiP  = hsh + ((size_t)(T - 16) << 18);
  float*  bias = (float*)(ws + BIAS_OFF);
  u32*    flg  = (u32*)(ws + FLAG_OFF);
  float*  out  = (float*)d_out;

  hipFuncSetAttribute((const void*)k_lstm,
                      hipFuncAttributeMaxDynamicSharedMemorySize, LDS_BYTES);

  k_setup<<<4352, 256, 0, stream>>>(Wif, Wii, Wio, Wic, Whf, Whi, Who, Whc,
                                    bif, bii, bio, bic, bhf, bhi, bho, bhc,
                                    x0, out, WcP, WiP, bias, hsh, flg, T * 256);
  k_lstm<<<256, 512, LDS_BYTES, stream>>>(WcP, WiP, bias, hsh, flg, out, T);
}

// Round 5
// 774.210 us; speedup vs baseline: 1.1420x; 1.1420x over previous
//
#include <hip/hip_runtime.h>
#include <stdint.h>

// Autoregressive LSTM, B=256, H=1024, T=128.
//  - x==h for steps >=2  => combined weights W = Wi+Wh (4 GEMMs/step)
//  - weights persistent in REGISTERS (B-frags, 128 VGPR/wave)
//  - A (=h[s-1]) staged into LDS per step via global_load_lds (16-deep swizzle)
//  - XCD-LOCAL recurrence: mt = physical XCC_ID (s_getreg), jt = per-XCD ticket.
//    1 WG/CU (LDS cap) x 256 CUs => exactly 32 WGs per XCD. h exchanged via
//    PLAIN stores/loads at fresh addresses -> coherent in the XCD's own L2
//    (no L3 round trip for bulk data). Only 4B flags go agent-scope (L3).
//  - single flag store per WG after per-wave drain + barrier (round-3 style)
//  - out (f32 trajectory) stored PLAIN after the flag: L2-acked, lazily
//    written back, off the inter-WG critical path.

#define BATCH 256
#define HID   1024

typedef __bf16 bf16_t;
typedef bf16_t bf16x8 __attribute__((ext_vector_type(8)));
typedef float  f32x16 __attribute__((ext_vector_type(16)));
typedef float  f32x4  __attribute__((ext_vector_type(4)));
typedef float  f32x2  __attribute__((ext_vector_type(2)));
typedef unsigned int u32;
typedef unsigned long long u64;

// ---- workspace layout (bytes) ----
// [0, 64MB)   : h shadow bf16 [T][256][1024]  (Wi overlaid on tail)
// [64MB,72MB) : combined weights Wc bf16 [4096][1024], row = j*4 + gate
// [72MB,+16K) : combined bias f32 [4096]
// [72MB+64K)  : flags u32 [T][8][32], then tickets u32[8]
#define WC_OFF    (64ull << 20)
#define BIAS_OFF  (72ull << 20)
#define FLAG_OFF  ((72ull << 20) + (1ull << 16))

// LDS: [0,65536) A region (32 rows x 2048B, 16-deep XOR swizzle)
//      [65536,131072) K-split partials [4][32][128] f32
//      [131072,+512) bias slice; [131584,+16) wginfo
#define LDS_BYTES 131648   // forces 1 WG/CU

__device__ __forceinline__ void gload_lds16(const void* g, void* l) {
  auto gp = reinterpret_cast<const __attribute__((address_space(1))) unsigned int*>(
      reinterpret_cast<uintptr_t>(g));
  auto lp = reinterpret_cast<__attribute__((address_space(3))) unsigned int*>(
      reinterpret_cast<uintptr_t>(l));
  __builtin_amdgcn_global_load_lds(gp, lp, 16, 0, 0);
}

// merged prep (blocks 0..4095: combine weights) + init (blocks 4096..4351)
__global__ __launch_bounds__(256) void k_setup(
    const float* __restrict__ wf, const float* __restrict__ wi_,
    const float* __restrict__ wo, const float* __restrict__ wc,
    const float* __restrict__ hf, const float* __restrict__ hi,
    const float* __restrict__ ho, const float* __restrict__ hc,
    const float* __restrict__ bf_, const float* __restrict__ bi_,
    const float* __restrict__ bo_, const float* __restrict__ bc_,
    const float* __restrict__ hbf, const float* __restrict__ hbi,
    const float* __restrict__ hbo, const float* __restrict__ hbc,
    const float* __restrict__ x0, float* __restrict__ out,
    bf16_t* __restrict__ Wc, bf16_t* __restrict__ Wi, float* __restrict__ bias,
    bf16_t* __restrict__ hsh, u32* __restrict__ flags, int nflags)
{
  int bid = blockIdx.x;
  if (bid < 4096) {                // ---- weight prep: row = j*4 + g ----
    int r = bid, j = r >> 2, g = r & 3;
    const float *wip, *whp, *bip, *bhp;
    switch (g) {
      case 0:  wip = wf;  whp = hf; bip = bf_; bhp = hbf; break;
      case 1:  wip = wi_; whp = hi; bip = bi_; bhp = hbi; break;
      case 2:  wip = wo;  whp = ho; bip = bo_; bhp = hbo; break;
      default: wip = wc;  whp = hc; bip = bc_; bhp = hbc; break;
    }
    int k = threadIdx.x * 4;
    f32x4 a = *(const f32x4*)(wip + (size_t)j * HID + k);
    f32x4 b = *(const f32x4*)(whp + (size_t)j * HID + k);
    union { bf16_t h[4]; u64 v; } pc, pi;
#pragma unroll
    for (int t = 0; t < 4; ++t) { pc.h[t] = (bf16_t)(a[t] + b[t]); pi.h[t] = (bf16_t)a[t]; }
    *(u64*)(Wc + (size_t)r * HID + k) = pc.v;
    *(u64*)(Wi + (size_t)r * HID + k) = pi.v;
    if (threadIdx.x == 0) bias[r] = bip[j] + bhp[j];
  } else {                         // ---- init: x0 -> out[0], hsh[0]; zero flags+tickets ----
    int gid = (bid - 4096) * 256 + threadIdx.x;   // 65536 threads x 4 elems
    int i = gid * 4;
    f32x4 v = *(const f32x4*)(x0 + i);
    __builtin_nontemporal_store(v, (f32x4*)(out + i));
    union { bf16_t h[4]; u64 u; } p;
#pragma unroll
    for (int t = 0; t < 4; ++t) p.h[t] = (bf16_t)v[t];
    *(u64*)(hsh + i) = p.u;
    if (gid < nflags) flags[gid] = 0;
  }
}

__global__ __launch_bounds__(512, 2) void k_lstm(
    const bf16_t* __restrict__ Wc, const bf16_t* __restrict__ Wi,
    const float* __restrict__ bias, bf16_t* __restrict__ hsh,
    u32* __restrict__ flags, u32* __restrict__ tick,
    float* __restrict__ out, int T)
{
  extern __shared__ char lds[];
  char*  plds   = lds + 65536;           // partials [4][32][128] f32
  float* blds   = (float*)(lds + 131072);
  u32*   wginfo = (u32*)(lds + 131584);

  const int tid  = threadIdx.x;
  // ---- self-assign role by PHYSICAL XCD (m09: HW_REG_XCC_ID works on gfx950) ----
  if (tid == 0) {
    u32 x;
    asm volatile("s_getreg_b32 %0, hwreg(HW_REG_XCC_ID)" : "=s"(x));
    x &= 7;
    u32 t = __hip_atomic_fetch_add(tick + x, 1u, __ATOMIC_RELAXED,
                                   __HIP_MEMORY_SCOPE_AGENT);
    wginfo[0] = x;
    wginfo[1] = t & 31;
  }
  __syncthreads();
  const int mt = wginfo[0];          // physical XCD = batch group (32 rows)
  const int jt = wginfo[1];          // 0..31: 32 hidden cols / 128 gate rows

  const int lane = tid & 63;
  const int wv   = tid >> 6;         // 0..7
  const int wn   = wv & 1;           // col half (2 tiles of 32 gate cols each)
  const int ks   = wv >> 1;          // k quarter (256 of 1024)
  const int al   = lane & 31, kh = lane >> 5;
  const int row0 = jt << 7;          // first gate row of this WG

  if (tid < 128) blds[tid] = bias[row0 + tid];

  // epilogue mapping: thread -> (batch row eb, hidden col pair jp)
  const int eb   = tid >> 4;         // 0..31
  const int jp   = (tid & 15) << 1;  // 0,2,..,30
  const int bswz = (eb & 7) << 4;
  const size_t eoff_base = ((size_t)((mt << 5) + eb) << 10) + (jt << 5) + jp;
  float cst0 = 0.f, cst1 = 0.f;      // c-state (2 cells/thread), in VGPRs

  const int aswz = (al & 15) << 4;   // 16-deep swizzle
  const int kb0  = (ks << 9) + (kh << 4);
  bf16x8 breg0[16], breg1[16];       // persistent B fragments (128 VGPRs)

  for (int s = 1; s < T; ++s) {
    // ---- B: poll own XCD's 32 producer flags (wave0, lane-parallel) ----
    if (s >= 2 && wv == 0) {
      const u32* f = flags + ((size_t)(s - 1) << 8) + (mt << 5);
      u32 v = (lane < 32)
          ? __hip_atomic_load(f + lane, __ATOMIC_RELAXED, __HIP_MEMORY_SCOPE_AGENT)
          : 1u;
      int guard = 0;
      while (!__all(v != 0) && guard < (1 << 20)) {
        __builtin_amdgcn_s_sleep(1);
        if (lane < 32 && v == 0)
          v = __hip_atomic_load(f + lane, __ATOMIC_RELAXED, __HIP_MEMORY_SCOPE_AGENT);
        ++guard;
      }
    }
    __syncthreads();                                    // C

    // ---- D: stage h[s-1] slice (32 rows x 2KB = 64KB) into LDS ----
    // producers are same-XCD => these plain loads hit the local L2
    {
      const char* hp = (const char*)hsh + ((size_t)(s - 1) << 19) + ((size_t)mt << 16);
#pragma unroll
      for (int c = 0; c < 8; ++c) {
        int d = (c << 13) + (tid << 4);
        int row = d >> 11, off = d & 2047;
        gload_lds16(hp + row * 2048 + (off ^ ((row & 15) << 4)), lds + d);
      }
    }
    if (s <= 2) {  // B-frags: step 1 = Wi (h==0), step 2 = combined Wc
      const bf16_t* WB  = (s == 1) ? Wi : Wc;
      const bf16_t* wb0 = WB + ((size_t)(row0 + (wn << 6) + al) << 10) + (ks << 8) + (kh << 3);
      const bf16_t* wb1 = wb0 + (32 << 10);
#pragma unroll
      for (int kk = 0; kk < 16; ++kk) {
        breg0[kk] = *(const bf16x8*)(wb0 + (kk << 4));
        breg1[kk] = *(const bf16x8*)(wb1 + (kk << 4));
      }
    }
    asm volatile("s_waitcnt vmcnt(0)" ::: "memory");    // E
    __syncthreads();                                    // F

    // ---- G: MFMA, 2 col-tiles per A read, K-range 256 per wave ----
    f32x16 acc0 = {}, acc1 = {};
    {
      const char* abase = lds + al * 2048;
#pragma unroll
      for (int kk = 0; kk < 16; ++kk) {
        bf16x8 a = *(const bf16x8*)(abase + ((kb0 + (kk << 5)) ^ aswz));
        acc0 = __builtin_amdgcn_mfma_f32_32x32x16_bf16(a, breg0[kk], acc0, 0, 0, 0);
        acc1 = __builtin_amdgcn_mfma_f32_32x32x16_bf16(a, breg1[kk], acc1, 0, 0, 0);
      }
    }

    // ---- H: write K-split partials (dedicated region) ----
#pragma unroll
    for (int r = 0; r < 16; ++r) {
      int prow = (r & 3) + ((r >> 2) << 3) + (kh << 2);
      char* pb = plds + (ks << 14) + prow * 512;
      int sw = (prow & 7) << 4;
      *(float*)(pb + ((((wn << 6) + al) << 2) ^ sw))      = acc0[r];
      *(float*)(pb + ((((wn << 6) + 32 + al) << 2) ^ sw)) = acc1[r];
    }
    __syncthreads();                                    // I

    // ---- J: epilogue — reduce 4 partials, gate math ----
    float hv[2];
#pragma unroll
    for (int e = 0; e < 2; ++e) {
      int cb = (jp + e) << 4;        // gate-quad byte offset
      int co = cb ^ bswz;
      const char* pb = plds + eb * 512;
      f32x4 p = *(const f32x4*)(pb + co);
      p += *(const f32x4*)(pb + 16384 + co);
      p += *(const f32x4*)(pb + 32768 + co);
      p += *(const f32x4*)(pb + 49152 + co);
      f32x4 bb = *(const f32x4*)((const char*)blds + cb);
      float xf = p[0] + bb[0], xi = p[1] + bb[1], xo = p[2] + bb[2], xc = p[3] + bb[3];
      float gf = 1.f / (1.f + __expf(-xf));
      float gi = 1.f / (1.f + __expf(-xi));
      float go = 1.f / (1.f + __expf(-xo));
      float cp = tanhf(xc);
      float &cs = e ? cst1 : cst0;
      cs = gf * cs + gi * cp;
      hv[e] = go * tanhf(cs);
    }

    // ---- K: h-shadow PLAIN store (fresh addr; stays in own-XCD L2) ----
    union { bf16_t h2[2]; u32 u; } pk;
    pk.h2[0] = (bf16_t)hv[0]; pk.h2[1] = (bf16_t)hv[1];
    *(u32*)(hsh + ((size_t)s << 18) + eoff_base) = pk.u;
    // ---- L: per-wave drain (own stores committed to L2) ----
    asm volatile("s_waitcnt vmcnt(0)" ::: "memory");
    __syncthreads();                                    // Z: whole WG committed
    // ---- M: single flag store (agent scope; meets consumer polls at L3) ----
    if (tid == 0)
      __hip_atomic_store(flags + ((size_t)s << 8) + (mt << 5) + jt, 1u,
                         __ATOMIC_RELAXED, __HIP_MEMORY_SCOPE_AGENT);
    asm volatile("" ::: "memory");
    // ---- N: out store AFTER flag, PLAIN (L2-acked, lazy writeback) ----
    f32x2 ov; ov[0] = hv[0]; ov[1] = hv[1];
    *(f32x2*)(out + ((size_t)s << 18) + eoff_base) = ov;
  }
}

extern "C" void kernel_launch(void* const* d_in, const int* in_sizes, int n_in,
                              void* d_out, int out_size, void* d_ws, size_t ws_size,
                              hipStream_t stream) {
  const float* Wif = (const float*)d_in[0];
  const float* bif = (const float*)d_in[1];
  const float* Wii = (const float*)d_in[2];
  const float* bii = (const float*)d_in[3];
  const float* Wio = (const float*)d_in[4];
  const float* bio = (const float*)d_in[5];
  const float* Wic = (const float*)d_in[6];
  const float* bic = (const float*)d_in[7];
  const float* Whf = (const float*)d_in[8];
  const float* bhf = (const float*)d_in[9];
  const float* Whi = (const float*)d_in[10];
  const float* bhi = (const float*)d_in[11];
  const float* Who = (const float*)d_in[12];
  const float* bho = (const float*)d_in[13];
  const float* Whc = (const float*)d_in[14];
  const float* bhc = (const float*)d_in[15];
  const float* x0  = (const float*)d_in[16];
  const int T = out_size / (BATCH * HID);          // 128

  char* ws = (char*)d_ws;
  bf16_t* hsh  = (bf16_t*)ws;
  bf16_t* WcP  = (bf16_t*)(ws + WC_OFF);
  // Wi (step-1 weights) overlaid on h-shadow tail (steps T-16..T-1): only read
  // during step 1's B-load, overwritten ~100 steps later.
  bf16_t* WiP  = hsh + ((size_t)(T - 16) << 18);
  float*  bias = (float*)(ws + BIAS_OFF);
  u32*    flg  = (u32*)(ws + FLAG_OFF);
  u32*    tick = flg + ((size_t)T << 8);
  float*  out  = (float*)d_out;

  hipFuncSetAttribute((const void*)k_lstm,
                      hipFuncAttributeMaxDynamicSharedMemorySize, LDS_BYTES);

  k_setup<<<4352, 256, 0, stream>>>(Wif, Wii, Wio, Wic, Whf, Whi, Who, Whc,
                                    bif, bii, bio, bic, bhf, bhi, bho, bhc,
                                    x0, out, WcP, WiP, bias, hsh, flg,
                                    T * 256 + 8);
  k_lstm<<<256, 512, LDS_BYTES, stream>>>(WcP, WiP, bias, hsh, flg, tick, out, T);
}